// Round 1
// baseline (653.771 us; speedup 1.0000x reference)
//
#include <hip/hip_runtime.h>

// WindowAttention3D: x(256,343,384) -> qkv -> per-(b,h) softmax attention (+rel bias) -> proj
// Strategy: bf16 MFMA everywhere, fp32 accum. 6 kernels on one stream.

#define M_TOT 87808   // 256*343
#define NTOK  343
#define NPAD  352
#define DIMC  384
#define NHEAD 12
#define QKVN  1152
#define BWIN  256

typedef __bf16 bf16x8 __attribute__((ext_vector_type(8)));
typedef float f32x4 __attribute__((ext_vector_type(4)));

__device__ __forceinline__ unsigned short bf16rne(float f) {
  unsigned int u = __float_as_uint(f);
  u += 0x7fffu + ((u >> 16) & 1u);
  return (unsigned short)(u >> 16);
}

__device__ __forceinline__ unsigned int packbf(float lo, float hi) {
  return (unsigned int)bf16rne(lo) | ((unsigned int)bf16rne(hi) << 16);
}

// ---------------- prep kernels ----------------

__global__ void cvt_x_kernel(const float* __restrict__ x, unsigned short* __restrict__ xb, int n8) {
  int i = blockIdx.x * 256 + threadIdx.x;
  if (i >= n8) return;
  const float4* xv = (const float4*)x + (size_t)i * 2;
  float4 a = xv[0], b = xv[1];
  uint4 o;
  o.x = packbf(a.x, a.y); o.y = packbf(a.z, a.w);
  o.z = packbf(b.x, b.y); o.w = packbf(b.z, b.w);
  ((uint4*)xb)[i] = o;
}

__global__ void prep_w_kernel(const float* __restrict__ qkv_w, const float* __restrict__ proj_w,
                              unsigned short* __restrict__ wqkvT, unsigned short* __restrict__ wprojT) {
  int tid = blockIdx.x * 256 + threadIdx.x;
  if (tid < QKVN * DIMC) {
    int n = tid / DIMC, k = tid - n * DIMC;
    wqkvT[tid] = bf16rne(qkv_w[(size_t)k * QKVN + n]);
  }
  if (tid < DIMC * DIMC) {
    int n = tid / DIMC, k = tid - n * DIMC;
    wprojT[tid] = bf16rne(proj_w[(size_t)k * DIMC + n]);
  }
}

// biasmat[h][i][j] = bias_table[rel_idx[i][j]][h] * log2(e); padded j -> 0
__global__ void prep_bias_kernel(const float* __restrict__ bias_table, const int* __restrict__ rel_idx,
                                 float* __restrict__ biasmat) {
  int tid = blockIdx.x * 256 + threadIdx.x;
  if (tid >= NTOK * NPAD) return;
  int i = tid / NPAD, j = tid - i * NPAD;
  const float LOG2E = 1.44269504088896340f;
  if (j < NTOK) {
    int idx = rel_idx[i * NTOK + j];
    #pragma unroll
    for (int h = 0; h < NHEAD; h++)
      biasmat[(size_t)h * (NTOK * NPAD) + tid] = bias_table[idx * NHEAD + h] * LOG2E;
  } else {
    #pragma unroll
    for (int h = 0; h < NHEAD; h++)
      biasmat[(size_t)h * (NTOK * NPAD) + tid] = 0.f;
  }
}

// ---------------- GEMM (A[M][K] bf16, Bt[N][K] bf16, +bias) ----------------

typedef const __attribute__((address_space(1))) unsigned int* gas_t;
typedef __attribute__((address_space(3))) unsigned int* las_t;

__device__ __forceinline__ void load16_lds(const void* g, void* l) {
  __builtin_amdgcn_global_load_lds((gas_t)g, (las_t)l, 16, 0, 0);
}

template<bool OUT_BF16>
__global__ __launch_bounds__(256, 3) void gemm_bt_kernel(
    const unsigned short* __restrict__ A, const unsigned short* __restrict__ Bt,
    const float* __restrict__ bias, void* __restrict__ outp,
    int M, int Nn, int K)
{
  __shared__ __attribute__((aligned(16))) unsigned short Atile[128 * 64];
  __shared__ __attribute__((aligned(16))) unsigned short Btile[128 * 64];
  const int t = threadIdx.x;
  const int lane = t & 63, w = t >> 6;
  const int q = lane >> 4, l15 = lane & 15;
  const int m0 = blockIdx.y * 128, n0 = blockIdx.x * 128;
  const int wm = w >> 1, wn = w & 1;

  f32x4 acc[4][4] = {};

  for (int kk = 0; kk < K; kk += 64) {
    // stage 128x64 A and Bt tiles; XOR-swizzle 16B chunks within each 64-elem row
    // (lds slot (r,c') holds global chunk (r, c'^(r&7)) -> conflict-free frag reads)
    #pragma unroll
    for (int i = 0; i < 4; i++) {
      int chunk = i * 256 + t;
      int r = chunk >> 3, cl = chunk & 7;
      int cg = cl ^ (r & 7);
      load16_lds(A + (size_t)(m0 + r) * K + kk + cg * 8, Atile + chunk * 8);
      load16_lds(Bt + (size_t)(n0 + r) * K + kk + cg * 8, Btile + chunk * 8);
    }
    __syncthreads();
    const bf16x8* As = (const bf16x8*)Atile;
    const bf16x8* Bs = (const bf16x8*)Btile;
    #pragma unroll
    for (int kq = 0; kq < 2; kq++) {
      bf16x8 af[4], bfr[4];
      #pragma unroll
      for (int mt = 0; mt < 4; mt++) {
        int m = wm * 64 + mt * 16 + l15;
        af[mt] = As[m * 8 + ((kq * 4 + q) ^ (m & 7))];
      }
      #pragma unroll
      for (int nt = 0; nt < 4; nt++) {
        int nr = wn * 64 + nt * 16 + l15;
        bfr[nt] = Bs[nr * 8 + ((kq * 4 + q) ^ (nr & 7))];
      }
      #pragma unroll
      for (int mt = 0; mt < 4; mt++)
        #pragma unroll
        for (int nt = 0; nt < 4; nt++)
          acc[mt][nt] = __builtin_amdgcn_mfma_f32_16x16x32_bf16(af[mt], bfr[nt], acc[mt][nt], 0, 0, 0);
    }
    __syncthreads();
  }

  // epilogue: C/D layout col=lane&15, row=(lane>>4)*4+reg
  #pragma unroll
  for (int nt = 0; nt < 4; nt++) {
    int n = n0 + wn * 64 + nt * 16 + l15;
    float bv = bias[n];
    #pragma unroll
    for (int mt = 0; mt < 4; mt++) {
      int mb = m0 + wm * 64 + mt * 16 + q * 4;
      #pragma unroll
      for (int r = 0; r < 4; r++) {
        float v = acc[mt][nt][r] + bv;
        size_t off = (size_t)(mb + r) * Nn + n;
        if (OUT_BF16) ((unsigned short*)outp)[off] = bf16rne(v);
        else          ((float*)outp)[off] = v;
      }
    }
  }
}

// ---------------- attention: one block per (b,h) ----------------

__global__ __launch_bounds__(256, 2) void attn_kernel(
    const unsigned short* __restrict__ qkvb,   // [M_TOT][1152] bf16
    const float* __restrict__ biasmat,         // [12][343][352] (pre * log2e)
    unsigned short* __restrict__ attnout)      // [M_TOT][384] bf16
{
  __shared__ __attribute__((aligned(16))) unsigned short Klds[NPAD * 40];  // K[j][d], stride 40
  __shared__ __attribute__((aligned(16))) unsigned short Vt[32 * 360];     // V^T[d][j], stride 360
  __shared__ __attribute__((aligned(16))) unsigned short Pbuf[4 * 640];    // per-wave P 16x32, stride 40
  const int bh = blockIdx.x;
  const int b = bh / NHEAD, h = bh - b * NHEAD;
  const int t = threadIdx.x;
  const int lane = t & 63, w = t >> 6;
  const int q = lane >> 4, l15 = lane & 15;

  const size_t base = (size_t)b * NTOK * QKVN;
  const unsigned short* Kg = qkvb + base + DIMC + h * 32;
  const unsigned short* Vg = qkvb + base + 2 * DIMC + h * 32;
  const unsigned short* Qg = qkvb + base + h * 32;

  // stage K rows and transposed V; zero-pad j in [343,352)
  #pragma unroll
  for (int i = 0; i < 6; i++) {
    int chunk = i * 256 + t;
    if (chunk < NPAD * 4) {
      int j = chunk >> 2, c = chunk & 3;
      uint4 kd = {0, 0, 0, 0}, vd = {0, 0, 0, 0};
      if (j < NTOK) {
        kd = *(const uint4*)(Kg + (size_t)j * QKVN + c * 8);
        vd = *(const uint4*)(Vg + (size_t)j * QKVN + c * 8);
      }
      *(uint4*)(Klds + j * 40 + c * 8) = kd;
      const unsigned short* vs = (const unsigned short*)&vd;
      #pragma unroll
      for (int u = 0; u < 8; u++)
        Vt[(c * 8 + u) * 360 + j] = vs[u];
    }
  }
  __syncthreads();

  const float* bh_bias = biasmat + (size_t)h * (NTOK * NPAD);
  const float CS = 0.17677669529663689f * 1.44269504088896340f;  // scale * log2e
  const bf16x8* Ks = (const bf16x8*)Klds;
  const bf16x8* Vs = (const bf16x8*)Vt;
  const bf16x8* Ps = (const bf16x8*)(Pbuf + w * 640);
  unsigned short* Pw = Pbuf + w * 640;

  for (int it = w; it < 22; it += 4) {
    // Q A-fragment straight from global: A[m=lane&15][k=(lane>>4)*8+j]
    int iq = it * 16 + l15; iq = iq > (NTOK - 1) ? (NTOK - 1) : iq;
    bf16x8 aq = *(const bf16x8*)(Qg + (size_t)iq * QKVN + q * 8);

    // S row-block [16][352] in 22 accumulators
    f32x4 s[22];
    #pragma unroll
    for (int jt = 0; jt < 22; jt++) {
      int j = jt * 16 + l15;
      f32x4 zero = {0.f, 0.f, 0.f, 0.f};
      s[jt] = __builtin_amdgcn_mfma_f32_16x16x32_bf16(aq, Ks[j * 5 + q], zero, 0, 0, 0);
    }

    // scale + bias (exp2 domain) + mask, row max
    int ib = it * 16 + q * 4;
    float mx[4] = {-3e38f, -3e38f, -3e38f, -3e38f};
    #pragma unroll
    for (int jt = 0; jt < 22; jt++) {
      int j = jt * 16 + l15;
      #pragma unroll
      for (int r = 0; r < 4; r++) {
        int i = ib + r; i = i > (NTOK - 1) ? (NTOK - 1) : i;
        float val = (j < NTOK) ? fmaf(s[jt][r], CS, bh_bias[(size_t)i * NPAD + j]) : -1e30f;
        s[jt][r] = val;
        mx[r] = fmaxf(mx[r], val);
      }
    }
    #pragma unroll
    for (int r = 0; r < 4; r++) {
      mx[r] = fmaxf(mx[r], __shfl_xor(mx[r], 1));
      mx[r] = fmaxf(mx[r], __shfl_xor(mx[r], 2));
      mx[r] = fmaxf(mx[r], __shfl_xor(mx[r], 4));
      mx[r] = fmaxf(mx[r], __shfl_xor(mx[r], 8));
    }
    float sm[4] = {0.f, 0.f, 0.f, 0.f};
    #pragma unroll
    for (int jt = 0; jt < 22; jt++) {
      #pragma unroll
      for (int r = 0; r < 4; r++) {
        float p = __builtin_amdgcn_exp2f(s[jt][r] - mx[r]);
        s[jt][r] = p;
        sm[r] += p;
      }
    }
    #pragma unroll
    for (int r = 0; r < 4; r++) {
      sm[r] += __shfl_xor(sm[r], 1);
      sm[r] += __shfl_xor(sm[r], 2);
      sm[r] += __shfl_xor(sm[r], 4);
      sm[r] += __shfl_xor(sm[r], 8);
    }

    // PV: P C-layout -> A-layout via per-wave LDS round-trip; 1/denom folded into epilogue
    f32x4 o0 = {0.f, 0.f, 0.f, 0.f}, o1 = {0.f, 0.f, 0.f, 0.f};
    #pragma unroll
    for (int jp = 0; jp < 11; jp++) {
      #pragma unroll
      for (int half = 0; half < 2; half++) {
        int jt = jp * 2 + half;
        #pragma unroll
        for (int r = 0; r < 4; r++)
          Pw[(q * 4 + r) * 40 + half * 16 + l15] = bf16rne(s[jt][r]);
      }
      bf16x8 ap = Ps[l15 * 5 + q];              // P[m=l15][k=q*8..]
      bf16x8 v0 = Vs[l15 * 45 + jp * 4 + q];    // V^T[d][j]
      bf16x8 v1 = Vs[(16 + l15) * 45 + jp * 4 + q];
      o0 = __builtin_amdgcn_mfma_f32_16x16x32_bf16(ap, v0, o0, 0, 0, 0);
      o1 = __builtin_amdgcn_mfma_f32_16x16x32_bf16(ap, v1, o1, 0, 0, 0);
    }

    #pragma unroll
    for (int r = 0; r < 4; r++) {
      int i = ib + r;
      if (i < NTOK) {
        float inv = __builtin_amdgcn_rcpf(sm[r]);
        size_t orow = ((size_t)b * NTOK + i) * DIMC + h * 32;
        attnout[orow + l15]      = bf16rne(o0[r] * inv);
        attnout[orow + 16 + l15] = bf16rne(o1[r] * inv);
      }
    }
  }
}

// ---------------- launch ----------------

extern "C" void kernel_launch(void* const* d_in, const int* in_sizes, int n_in,
                              void* d_out, int out_size, void* d_ws, size_t ws_size,
                              hipStream_t stream) {
  const float* x          = (const float*)d_in[0];
  const float* qkv_w      = (const float*)d_in[1];
  const float* qkv_b      = (const float*)d_in[2];
  const float* proj_w     = (const float*)d_in[3];
  const float* proj_b     = (const float*)d_in[4];
  const float* bias_table = (const float*)d_in[5];
  const int*   rel_idx    = (const int*)d_in[6];

  char* p = (char*)d_ws;
  unsigned short* xb      = (unsigned short*)p; p += (size_t)M_TOT * DIMC * 2;   // 67.4 MB
  unsigned short* wqkvT   = (unsigned short*)p; p += (size_t)QKVN * DIMC * 2;    // 0.9 MB
  unsigned short* wprojT  = (unsigned short*)p; p += (size_t)DIMC * DIMC * 2;    // 0.3 MB
  float*          biasmat = (float*)p;          p += (size_t)NHEAD * NTOK * NPAD * 4; // 5.8 MB
  unsigned short* qkvb    = (unsigned short*)p; p += (size_t)M_TOT * QKVN * 2;   // 202.3 MB
  unsigned short* attnout = (unsigned short*)p; p += (size_t)M_TOT * DIMC * 2;   // 67.4 MB
  // total ~344 MB

  cvt_x_kernel<<<(M_TOT * DIMC / 8 + 255) / 256, 256, 0, stream>>>(x, xb, M_TOT * DIMC / 8);
  prep_w_kernel<<<(QKVN * DIMC + 255) / 256, 256, 0, stream>>>(qkv_w, proj_w, wqkvT, wprojT);
  prep_bias_kernel<<<(NTOK * NPAD + 255) / 256, 256, 0, stream>>>(bias_table, rel_idx, biasmat);
  gemm_bt_kernel<true><<<dim3(QKVN / 128, M_TOT / 128), 256, 0, stream>>>(
      xb, wqkvT, qkv_b, (void*)qkvb, M_TOT, QKVN, DIMC);
  attn_kernel<<<BWIN * NHEAD, 256, 0, stream>>>(qkvb, biasmat, attnout);
  gemm_bt_kernel<false><<<dim3(DIMC / 128, M_TOT / 128), 256, 0, stream>>>(
      attnout, wprojT, proj_b, d_out, M_TOT, DIMC, DIMC);
}